// Round 1
// baseline (1818.837 us; speedup 1.0000x reference)
//
#include <hip/hip_runtime.h>

#define HH 64
#define G3 192
#define TT 2048
#define BB 256
#define YSZ (BB*TT)   // y elements before hT in d_out

__device__ __forceinline__ float sigmoid_f(float v) {
    return 1.0f / (1.0f + __expf(-v));
}
__device__ __forceinline__ float tanh_f(float v) {
    // tanh(v) = 1 - 2/(exp(2v)+1); saturates correctly at +-inf
    return 1.0f - 2.0f / (1.0f + __expf(2.0f * v));
}

__global__ __launch_bounds__(256, 1)
void gru_fused(const float* __restrict__ x,      // [B,T,1]
               const float* __restrict__ h0in,   // [2,B,H]
               const float* __restrict__ W_ih0,  // [192,1]
               const float* __restrict__ W_hh0,  // [192,64]
               const float* __restrict__ b_ih0,  // [192]
               const float* __restrict__ b_hh0,  // [192]
               const float* __restrict__ W_ih1,  // [192,64]
               const float* __restrict__ W_hh1,  // [192,64]
               const float* __restrict__ b_ih1,  // [192]
               const float* __restrict__ b_hh1,  // [192]
               const float* __restrict__ Wh1,    // [64,64]
               const float* __restrict__ bh1,    // [64]
               const float* __restrict__ Wh2,    // [1,64]
               const float* __restrict__ bh2,    // [1]
               float* __restrict__ out)          // y [B*T] ++ hT [2,B,H]
{
    const int b   = blockIdx.x;
    const int tid = threadIdx.x;

    __shared__ __align__(16) float h0_lds[HH];
    __shared__ __align__(16) float h1_lds[HH];
    __shared__ __align__(16) float gh0_lds[G3];
    __shared__ __align__(16) float gx1_lds[G3];
    __shared__ __align__(16) float gh1_lds[G3];
    __shared__ __align__(16) float x_lds[TT];

    // ---- preload x row (coalesced float4), init h ----
    {
        const float4* xs = reinterpret_cast<const float4*>(x + (size_t)b * TT);
        float4*       xd = reinterpret_cast<float4*>(x_lds);
        for (int k = tid; k < TT/4; k += 256) xd[k] = xs[k];
    }
    if (tid < HH) {
        h0_lds[tid] = h0in[          b*HH + tid];
        h1_lds[tid] = h0in[BB*HH +   b*HH + tid];
    }

    // ---- weights into registers ----
    // threads 0..191: row tid of W_hh0 (w0), W_ih1 (wi1), W_hh1 (wh1r)
    // threads 192..255: Wh1 row (tid-192) aliased into w0 (saves 64 VGPRs)
    float w0[HH], wi1[HH], wh1r[HH];
    float bias_gh0 = 0.f, bias_gx1 = 0.f, bias_gh1 = 0.f;
    float wh2_r = 0.f, bias_head = 0.f, bh2_s = 0.f;
    float wih0_r=0.f, wih0_z=0.f, wih0_n=0.f, bih0_r=0.f, bih0_z=0.f, bih0_n=0.f;

    if (tid < G3) {
        #pragma unroll
        for (int k = 0; k < 16; ++k) {
            float4 v;
            v = reinterpret_cast<const float4*>(W_hh0 + tid*HH)[k];
            w0  [4*k]=v.x; w0  [4*k+1]=v.y; w0  [4*k+2]=v.z; w0  [4*k+3]=v.w;
            v = reinterpret_cast<const float4*>(W_ih1 + tid*HH)[k];
            wi1 [4*k]=v.x; wi1 [4*k+1]=v.y; wi1 [4*k+2]=v.z; wi1 [4*k+3]=v.w;
            v = reinterpret_cast<const float4*>(W_hh1 + tid*HH)[k];
            wh1r[4*k]=v.x; wh1r[4*k+1]=v.y; wh1r[4*k+2]=v.z; wh1r[4*k+3]=v.w;
        }
        bias_gh0 = b_hh0[tid];
        bias_gx1 = b_ih1[tid];
        bias_gh1 = b_hh1[tid];
    } else {
        const int j = tid - G3;
        #pragma unroll
        for (int k = 0; k < 16; ++k) {
            float4 v = reinterpret_cast<const float4*>(Wh1 + j*HH)[k];
            w0[4*k]=v.x; w0[4*k+1]=v.y; w0[4*k+2]=v.z; w0[4*k+3]=v.w;
        }
        wh2_r     = Wh2[j];
        bias_head = bh1[j];
        bh2_s     = bh2[0];
    }
    if (tid >= 64 && tid < 128) {
        const int j = tid - 64;
        wih0_r = W_ih0[j];        bih0_r = b_ih0[j];
        wih0_z = W_ih0[j+64];     bih0_z = b_ih0[j+64];
        wih0_n = W_ih0[j+128];    bih0_n = b_ih0[j+128];
    }

    __syncthreads();

    const float4* h04 = reinterpret_cast<const float4*>(h0_lds);
    const float4* h14 = reinterpret_cast<const float4*>(h1_lds);

    // Software pipeline, 2 barriers per iteration:
    //   A(i): gh0[i] = W_hh0@h0^i ; gx1[i-1] = W_ih1@h0^i ; gh1[i-1] = W_hh1@h1^(i-1)
    //         wave3: y[i-2] = head(h1^(i-1))
    //   B(i): combine1 -> h1^i ; combine0 -> h0^(i+1)
    for (int i = 0; i <= TT + 1; ++i) {
        // ---------------- Phase A ----------------
        if (tid < G3) {
            float a0 = bias_gh0, a1 = bias_gx1, a2 = bias_gh1;
            #pragma unroll
            for (int k = 0; k < 16; ++k) {
                float4 u = h04[k];   // broadcast ds_read_b128
                float4 v = h14[k];
                a0 = fmaf(w0  [4*k+0], u.x, a0);
                a1 = fmaf(wi1 [4*k+0], u.x, a1);
                a2 = fmaf(wh1r[4*k+0], v.x, a2);
                a0 = fmaf(w0  [4*k+1], u.y, a0);
                a1 = fmaf(wi1 [4*k+1], u.y, a1);
                a2 = fmaf(wh1r[4*k+1], v.y, a2);
                a0 = fmaf(w0  [4*k+2], u.z, a0);
                a1 = fmaf(wi1 [4*k+2], u.z, a1);
                a2 = fmaf(wh1r[4*k+2], v.z, a2);
                a0 = fmaf(w0  [4*k+3], u.w, a0);
                a1 = fmaf(wi1 [4*k+3], u.w, a1);
                a2 = fmaf(wh1r[4*k+3], v.w, a2);
            }
            gh0_lds[tid] = a0;
            gx1_lds[tid] = a1;
            gh1_lds[tid] = a2;
        } else {
            // wave 3: head for step (i-2), reads h1^(i-1) (stable this phase)
            float s = bias_head;
            #pragma unroll
            for (int k = 0; k < 16; ++k) {
                float4 v = h14[k];
                s = fmaf(w0[4*k+0], v.x, s);
                s = fmaf(w0[4*k+1], v.y, s);
                s = fmaf(w0[4*k+2], v.z, s);
                s = fmaf(w0[4*k+3], v.w, s);
            }
            float p = fmaxf(s, 0.f) * wh2_r;
            #pragma unroll
            for (int m = 1; m < 64; m <<= 1) p += __shfl_xor(p, m, 64);
            if (tid == G3 && i >= 2) {
                out[(size_t)b * TT + (i - 2)] = p + bh2_s;
            }
        }
        __syncthreads();

        // ---------------- Phase B ----------------
        if (tid < 64) {
            // layer-1 combine for step (i-1)
            const int j = tid;
            float xr = gx1_lds[j], xz = gx1_lds[j+64], xn = gx1_lds[j+128];
            float hr = gh1_lds[j], hz = gh1_lds[j+64], hn = gh1_lds[j+128];
            float r = sigmoid_f(xr + hr);
            float z = sigmoid_f(xz + hz);
            float n = tanh_f(fmaf(r, hn, xn));
            float hprev = h1_lds[j];
            float hnew  = fmaf(z, hprev - n, n);   // (1-z)*n + z*h
            if (i >= 1 && i <= TT) h1_lds[j] = hnew;
        } else if (tid < 128) {
            // layer-0 combine for step i
            const int j  = tid - 64;
            const int xi = (i < TT) ? i : (TT - 1);
            float xv = x_lds[xi];
            float xr = fmaf(xv, wih0_r, bih0_r);
            float xz = fmaf(xv, wih0_z, bih0_z);
            float xn = fmaf(xv, wih0_n, bih0_n);
            float hr = gh0_lds[j], hz = gh0_lds[j+64], hn = gh0_lds[j+128];
            float r = sigmoid_f(xr + hr);
            float z = sigmoid_f(xz + hz);
            float n = tanh_f(fmaf(r, hn, xn));
            float hprev = h0_lds[j];
            float hnew  = fmaf(z, hprev - n, n);
            if (i < TT) h0_lds[j] = hnew;
        }
        __syncthreads();
    }

    // final hidden states: hT[2,B,H]
    if (tid < HH) {
        out[YSZ +            b*HH + tid] = h0_lds[tid];
        out[YSZ + BB*HH +    b*HH + tid] = h1_lds[tid];
    }
}

extern "C" void kernel_launch(void* const* d_in, const int* in_sizes, int n_in,
                              void* d_out, int out_size, void* d_ws, size_t ws_size,
                              hipStream_t stream) {
    const float* x     = (const float*)d_in[0];
    const float* h0in  = (const float*)d_in[1];
    const float* W_ih0 = (const float*)d_in[2];
    const float* W_hh0 = (const float*)d_in[3];
    const float* b_ih0 = (const float*)d_in[4];
    const float* b_hh0 = (const float*)d_in[5];
    const float* W_ih1 = (const float*)d_in[6];
    const float* W_hh1 = (const float*)d_in[7];
    const float* b_ih1 = (const float*)d_in[8];
    const float* b_hh1 = (const float*)d_in[9];
    const float* Wh1   = (const float*)d_in[10];
    const float* bh1   = (const float*)d_in[11];
    const float* Wh2   = (const float*)d_in[12];
    const float* bh2   = (const float*)d_in[13];
    float* out = (float*)d_out;

    gru_fused<<<dim3(BB), dim3(256), 0, stream>>>(
        x, h0in, W_ih0, W_hh0, b_ih0, b_hh0,
        W_ih1, W_hh1, b_ih1, b_hh1, Wh1, bh1, Wh2, bh2, out);
}

// Round 2
// 1701.934 us; speedup vs baseline: 1.0687x; 1.0687x over previous
//
#include <hip/hip_runtime.h>

#define HH 64
#define TT 2048
#define BB 256
#define YSZ (BB*TT)   // y elements before hT in d_out

__device__ __forceinline__ float sigmoid_f(float v) {
    return 1.0f / (1.0f + __expf(-v));
}
__device__ __forceinline__ float tanh_f(float v) {
    return 1.0f - 2.0f / (1.0f + __expf(2.0f * v));
}

// 512 threads = 8 waves (2 per SIMD). Dot products k-split across thread pairs
// (half = tid>>8). Gate threads hold 96 weight floats as float4[8]x3 -> VGPRs.
__global__ __launch_bounds__(512, 2)
void gru_fused(const float* __restrict__ x,      // [B,T,1]
               const float* __restrict__ h0in,   // [2,B,H]
               const float* __restrict__ W_ih0,  // [192,1]
               const float* __restrict__ W_hh0,  // [192,64]
               const float* __restrict__ b_ih0,  // [192]
               const float* __restrict__ b_hh0,  // [192]
               const float* __restrict__ W_ih1,  // [192,64]
               const float* __restrict__ W_hh1,  // [192,64]
               const float* __restrict__ b_ih1,  // [192]
               const float* __restrict__ b_hh1,  // [192]
               const float* __restrict__ Wh1,    // [64,64]
               const float* __restrict__ bh1,    // [64]
               const float* __restrict__ Wh2,    // [1,64]
               const float* __restrict__ bh2,    // [1]
               float* __restrict__ out)          // y [B*T] ++ hT [2,B,H]
{
    const int b    = blockIdx.x;
    const int tid  = threadIdx.x;
    const int t    = tid & 255;   // role id within half-group
    const int half = tid >> 8;    // k-half: 0 -> k in [0,32), 1 -> [32,64)
    const int ko   = half << 5;

    __shared__ __align__(16) float h0_lds[HH];
    __shared__ __align__(16) float h1_lds[HH];
    __shared__ __align__(16) float part[2 * 192 * 4]; // float4 per (half,row): {gh0,gx1,gh1,pad}
    __shared__ __align__(16) float ph[2 * 64];        // head partials
    __shared__ __align__(16) float x_lds[TT];

    // ---- preload x row (coalesced float4), init h ----
    {
        const float4* xs = reinterpret_cast<const float4*>(x + (size_t)b * TT);
        float4*       xd = reinterpret_cast<float4*>(x_lds);
        for (int k = tid; k < TT / 4; k += 512) xd[k] = xs[k];
    }
    if (tid < HH) {
        h0_lds[tid] = h0in[           b * HH + tid];
        h1_lds[tid] = h0in[BB * HH +  b * HH + tid];
    }

    // ---- per-thread weights (k-half slices) ----
    float4 wA[8], wB[8], wC[8];
    float bA = 0.f, bB = 0.f, bC = 0.f;
    if (t < 192) {
        const float4* pa = reinterpret_cast<const float4*>(W_hh0 + t * HH + ko);
        const float4* pb = reinterpret_cast<const float4*>(W_ih1 + t * HH + ko);
        const float4* pc = reinterpret_cast<const float4*>(W_hh1 + t * HH + ko);
        #pragma unroll
        for (int k = 0; k < 8; ++k) { wA[k] = pa[k]; wB[k] = pb[k]; wC[k] = pc[k]; }
        if (half == 0) { bA = b_hh0[t]; bB = b_ih1[t]; bC = b_hh1[t]; }
    } else {
        const float4* pa = reinterpret_cast<const float4*>(Wh1 + (t - 192) * HH + ko);
        #pragma unroll
        for (int k = 0; k < 8; ++k) { wA[k] = pa[k]; wB[k] = pa[k]; wC[k] = pa[k]; }
    }
    float wih0_r = 0.f, wih0_z = 0.f, wih0_n = 0.f;
    float bih0_r = 0.f, bih0_z = 0.f, bih0_n = 0.f;
    if (tid >= 64 && tid < 128) {
        const int j = tid - 64;
        wih0_r = W_ih0[j];       bih0_r = b_ih0[j];
        wih0_z = W_ih0[j + 64];  bih0_z = b_ih0[j + 64];
        wih0_n = W_ih0[j + 128]; bih0_n = b_ih0[j + 128];
    }
    float wh2_r = 0.f, bhead = 0.f, bh2_s = 0.f;
    if (tid >= 448) {
        const int j = tid - 448;
        wh2_r = Wh2[j]; bhead = bh1[j]; bh2_s = bh2[0];
    }

    __syncthreads();

    const float4* h0q   = reinterpret_cast<const float4*>(h0_lds + ko);
    const float4* h1q   = reinterpret_cast<const float4*>(h1_lds + ko);
    float4*       part4 = reinterpret_cast<float4*>(part);

    // Pipeline (same schedule as baseline), 2 barriers/iter:
    //   A(i): partial gh0(i) = W_hh0@h0^i ; gx1(i-1) = W_ih1@h0^i ;
    //         gh1(i-1) = W_hh1@h1^(i-1) ; head partial from h1^(i-1)
    //   B(i): combine layer-1 -> h1^i ; combine layer-0 -> h0^(i+1) ; y[i-2]
    for (int i = 0; i <= TT + 1; ++i) {
        // ---------------- Phase A: partial dots (k-half) ----------------
        if (t < 192) {
            float a0 = bA, a1 = bB, a2 = bC;
            #pragma unroll
            for (int k = 0; k < 8; ++k) {
                float4 u = h0q[k];   // broadcast reads
                float4 v = h1q[k];
                a0 = fmaf(wA[k].x, u.x, a0); a1 = fmaf(wB[k].x, u.x, a1); a2 = fmaf(wC[k].x, v.x, a2);
                a0 = fmaf(wA[k].y, u.y, a0); a1 = fmaf(wB[k].y, u.y, a1); a2 = fmaf(wC[k].y, v.y, a2);
                a0 = fmaf(wA[k].z, u.z, a0); a1 = fmaf(wB[k].z, u.z, a1); a2 = fmaf(wC[k].z, v.z, a2);
                a0 = fmaf(wA[k].w, u.w, a0); a1 = fmaf(wB[k].w, u.w, a1); a2 = fmaf(wC[k].w, v.w, a2);
            }
            part4[half * 192 + t] = make_float4(a0, a1, a2, 0.f);  // one ds_write_b128
        } else {
            float s = 0.f;
            #pragma unroll
            for (int k = 0; k < 8; ++k) {
                float4 v = h1q[k];
                s = fmaf(wA[k].x, v.x, s); s = fmaf(wA[k].y, v.y, s);
                s = fmaf(wA[k].z, v.z, s); s = fmaf(wA[k].w, v.w, s);
            }
            ph[half * 64 + (t - 192)] = s;
        }
        __syncthreads();

        // ---------------- Phase B: combines ----------------
        if (tid < 64) {
            // layer-1 combine for step (i-1)
            const int j = tid;
            float4 q0r = part4[j];       float4 q1r = part4[192 + j];
            float4 q0z = part4[j + 64];  float4 q1z = part4[192 + j + 64];
            float4 q0n = part4[j + 128]; float4 q1n = part4[192 + j + 128];
            float r = sigmoid_f(q0r.y + q1r.y + q0r.z + q1r.z);
            float z = sigmoid_f(q0z.y + q1z.y + q0z.z + q1z.z);
            float n = tanh_f(fmaf(r, q0n.z + q1n.z, q0n.y + q1n.y));
            if (i >= 1 && i <= TT) {
                float hp = h1_lds[j];
                h1_lds[j] = fmaf(z, hp - n, n);   // (1-z)*n + z*h
            }
        } else if (tid < 128) {
            // layer-0 combine for step i
            const int j  = tid - 64;
            const int xi = (i < TT) ? i : (TT - 1);
            float4 q0r = part4[j];       float4 q1r = part4[192 + j];
            float4 q0z = part4[j + 64];  float4 q1z = part4[192 + j + 64];
            float4 q0n = part4[j + 128]; float4 q1n = part4[192 + j + 128];
            float xv = x_lds[xi];
            float r = sigmoid_f(fmaf(xv, wih0_r, bih0_r) + q0r.x + q1r.x);
            float z = sigmoid_f(fmaf(xv, wih0_z, bih0_z) + q0z.x + q1z.x);
            float n = tanh_f(fmaf(r, q0n.x + q1n.x, fmaf(xv, wih0_n, bih0_n)));
            if (i < TT) {
                float hp = h0_lds[j];
                h0_lds[j] = fmaf(z, hp - n, n);
            }
        } else if (tid >= 448) {
            // head combine + reduce for y[i-2]
            const int j = tid - 448;
            float s = ph[j] + ph[64 + j] + bhead;
            float p = fmaxf(s, 0.f) * wh2_r;
            #pragma unroll
            for (int m = 1; m < 64; m <<= 1) p += __shfl_xor(p, m, 64);
            if (tid == 448 && i >= 2) out[(size_t)b * TT + (i - 2)] = p + bh2_s;
        }
        __syncthreads();
    }

    // final hidden states: hT[2,B,H]
    if (tid < HH) {
        out[YSZ +           b * HH + tid] = h0_lds[tid];
        out[YSZ + BB * HH + b * HH + tid] = h1_lds[tid];
    }
}

extern "C" void kernel_launch(void* const* d_in, const int* in_sizes, int n_in,
                              void* d_out, int out_size, void* d_ws, size_t ws_size,
                              hipStream_t stream) {
    const float* x     = (const float*)d_in[0];
    const float* h0in  = (const float*)d_in[1];
    const float* W_ih0 = (const float*)d_in[2];
    const float* W_hh0 = (const float*)d_in[3];
    const float* b_ih0 = (const float*)d_in[4];
    const float* b_hh0 = (const float*)d_in[5];
    const float* W_ih1 = (const float*)d_in[6];
    const float* W_hh1 = (const float*)d_in[7];
    const float* b_ih1 = (const float*)d_in[8];
    const float* b_hh1 = (const float*)d_in[9];
    const float* Wh1   = (const float*)d_in[10];
    const float* bh1   = (const float*)d_in[11];
    const float* Wh2   = (const float*)d_in[12];
    const float* bh2   = (const float*)d_in[13];
    float* out = (float*)d_out;

    gru_fused<<<dim3(BB), dim3(512), 0, stream>>>(
        x, h0in, W_ih0, W_hh0, b_ih0, b_hh0,
        W_ih1, W_hh1, b_ih1, b_hh1, Wh1, bh1, Wh2, bh2, out);
}

// Round 3
// 1696.756 us; speedup vs baseline: 1.0719x; 1.0031x over previous
//
#include <hip/hip_runtime.h>

#define HH 64
#define TT 2048
#define BB 256
#define YSZ (BB*TT)   // y elements before hT in d_out

__device__ __forceinline__ float sigmoid_f(float v) {
    return 1.0f / (1.0f + __expf(-v));
}
__device__ __forceinline__ float tanh_f(float v) {
    return 1.0f - 2.0f / (1.0f + __expf(2.0f * v));
}

// 512 threads = 8 waves (2/SIMD). Dot products k-split across thread pairs
// (half = tid>>8). Weights held in 24 NAMED float4 registers per thread
// (arrays spilled to scratch in rounds 1-2: VGPR_Count 124/88 < needed 96+).
__global__ __launch_bounds__(512, 1)
void gru_fused(const float* __restrict__ x,      // [B,T,1]
               const float* __restrict__ h0in,   // [2,B,H]
               const float* __restrict__ W_ih0,  // [192,1]
               const float* __restrict__ W_hh0,  // [192,64]
               const float* __restrict__ b_ih0,  // [192]
               const float* __restrict__ b_hh0,  // [192]
               const float* __restrict__ W_ih1,  // [192,64]
               const float* __restrict__ W_hh1,  // [192,64]
               const float* __restrict__ b_ih1,  // [192]
               const float* __restrict__ b_hh1,  // [192]
               const float* __restrict__ Wh1,    // [64,64]
               const float* __restrict__ bh1,    // [64]
               const float* __restrict__ Wh2,    // [1,64]
               const float* __restrict__ bh2,    // [1]
               float* __restrict__ out)          // y [B*T] ++ hT [2,B,H]
{
    const int b    = blockIdx.x;
    const int tid  = threadIdx.x;
    const int t    = tid & 255;   // role id within half-group
    const int half = tid >> 8;    // k-half: 0 -> k in [0,32), 1 -> [32,64)
    const int ko   = half << 5;

    __shared__ __align__(16) float h0_lds[HH];
    __shared__ __align__(16) float h1_lds[HH];
    __shared__ __align__(16) float part[2 * 192 * 4]; // float4 per (half,row): {gh0,gx1,gh1,pad}
    __shared__ __align__(16) float ph[2 * 64];        // head partials
    __shared__ __align__(16) float x_lds[TT];

    // ---- preload x row (coalesced float4), init h ----
    {
        const float4* xs = reinterpret_cast<const float4*>(x + (size_t)b * TT);
        float4*       xd = reinterpret_cast<float4*>(x_lds);
        for (int k = tid; k < TT / 4; k += 512) xd[k] = xs[k];
    }
    if (tid < HH) {
        h0_lds[tid] = h0in[           b * HH + tid];
        h1_lds[tid] = h0in[BB * HH +  b * HH + tid];
    }

    // ---- per-thread weights in NAMED registers (k-half slices) ----
    float4 wa0, wa1, wa2, wa3, wa4, wa5, wa6, wa7;
    float4 wb0, wb1, wb2, wb3, wb4, wb5, wb6, wb7;
    float4 wc0, wc1, wc2, wc3, wc4, wc5, wc6, wc7;
    float bA = 0.f, bB = 0.f, bC = 0.f;
    if (t < 192) {
        const float4* pa = reinterpret_cast<const float4*>(W_hh0 + t * HH + ko);
        const float4* pb = reinterpret_cast<const float4*>(W_ih1 + t * HH + ko);
        const float4* pc = reinterpret_cast<const float4*>(W_hh1 + t * HH + ko);
        wa0 = pa[0]; wb0 = pb[0]; wc0 = pc[0];
        wa1 = pa[1]; wb1 = pb[1]; wc1 = pc[1];
        wa2 = pa[2]; wb2 = pb[2]; wc2 = pc[2];
        wa3 = pa[3]; wb3 = pb[3]; wc3 = pc[3];
        wa4 = pa[4]; wb4 = pb[4]; wc4 = pc[4];
        wa5 = pa[5]; wb5 = pb[5]; wc5 = pc[5];
        wa6 = pa[6]; wb6 = pb[6]; wc6 = pc[6];
        wa7 = pa[7]; wb7 = pb[7]; wc7 = pc[7];
        if (half == 0) { bA = b_hh0[t]; bB = b_ih1[t]; bC = b_hh1[t]; }
    } else {
        const float4* pa = reinterpret_cast<const float4*>(Wh1 + (t - 192) * HH + ko);
        wa0 = pa[0]; wa1 = pa[1]; wa2 = pa[2]; wa3 = pa[3];
        wa4 = pa[4]; wa5 = pa[5]; wa6 = pa[6]; wa7 = pa[7];
        wb0 = wa0; wb1 = wa1; wb2 = wa2; wb3 = wa3;
        wb4 = wa4; wb5 = wa5; wb6 = wa6; wb7 = wa7;
        wc0 = wa0; wc1 = wa1; wc2 = wa2; wc3 = wa3;
        wc4 = wa4; wc5 = wa5; wc6 = wa6; wc7 = wa7;
    }
    float wih0_r = 0.f, wih0_z = 0.f, wih0_n = 0.f;
    float bih0_r = 0.f, bih0_z = 0.f, bih0_n = 0.f;
    if (tid >= 64 && tid < 128) {
        const int j = tid - 64;
        wih0_r = W_ih0[j];       bih0_r = b_ih0[j];
        wih0_z = W_ih0[j + 64];  bih0_z = b_ih0[j + 64];
        wih0_n = W_ih0[j + 128]; bih0_n = b_ih0[j + 128];
    }
    float wh2_r = 0.f, bhead = 0.f, bh2_s = 0.f;
    if (tid >= 448) {
        const int j = tid - 448;
        wh2_r = Wh2[j]; bhead = bh1[j]; bh2_s = bh2[0];
    }

    __syncthreads();

    const float4* h0q   = reinterpret_cast<const float4*>(h0_lds + ko);
    const float4* h1q   = reinterpret_cast<const float4*>(h1_lds + ko);
    float4*       part4 = reinterpret_cast<float4*>(part);

#define GSTEP(i) { float4 u = h0q[i]; float4 v = h1q[i]; \
    a0 = fmaf(wa##i.x, u.x, a0); a1 = fmaf(wb##i.x, u.x, a1); a2 = fmaf(wc##i.x, v.x, a2); \
    a0 = fmaf(wa##i.y, u.y, a0); a1 = fmaf(wb##i.y, u.y, a1); a2 = fmaf(wc##i.y, v.y, a2); \
    a0 = fmaf(wa##i.z, u.z, a0); a1 = fmaf(wb##i.z, u.z, a1); a2 = fmaf(wc##i.z, v.z, a2); \
    a0 = fmaf(wa##i.w, u.w, a0); a1 = fmaf(wb##i.w, u.w, a1); a2 = fmaf(wc##i.w, v.w, a2); }
#define HSTEP(i) { float4 v = h1q[i]; \
    s = fmaf(wa##i.x, v.x, s); s = fmaf(wa##i.y, v.y, s); \
    s = fmaf(wa##i.z, v.z, s); s = fmaf(wa##i.w, v.w, s); }

    // Pipeline, 2 barriers/iter:
    //   A(i): partial gh0(i)=W_hh0@h0^i ; gx1(i-1)=W_ih1@h0^i ;
    //         gh1(i-1)=W_hh1@h1^(i-1) ; head partial from h1^(i-1)
    //   B(i): combine layer-1 -> h1^i ; combine layer-0 -> h0^(i+1) ; y[i-2]
    for (int i = 0; i <= TT + 1; ++i) {
        // ---------------- Phase A: partial dots (k-half) ----------------
        if (t < 192) {
            float a0 = bA, a1 = bB, a2 = bC;
            GSTEP(0) GSTEP(1) GSTEP(2) GSTEP(3)
            GSTEP(4) GSTEP(5) GSTEP(6) GSTEP(7)
            part4[half * 192 + t] = make_float4(a0, a1, a2, 0.f);  // one ds_write_b128
        } else {
            float s = 0.f;
            HSTEP(0) HSTEP(1) HSTEP(2) HSTEP(3)
            HSTEP(4) HSTEP(5) HSTEP(6) HSTEP(7)
            ph[half * 64 + (t - 192)] = s;
        }
        __syncthreads();

        // ---------------- Phase B: combines ----------------
        if (tid < 64) {
            // layer-1 combine for step (i-1)
            const int j = tid;
            float4 q0r = part4[j];       float4 q1r = part4[192 + j];
            float4 q0z = part4[j + 64];  float4 q1z = part4[192 + j + 64];
            float4 q0n = part4[j + 128]; float4 q1n = part4[192 + j + 128];
            float r = sigmoid_f(q0r.y + q1r.y + q0r.z + q1r.z);
            float z = sigmoid_f(q0z.y + q1z.y + q0z.z + q1z.z);
            float n = tanh_f(fmaf(r, q0n.z + q1n.z, q0n.y + q1n.y));
            if (i >= 1 && i <= TT) {
                float hp = h1_lds[j];
                h1_lds[j] = fmaf(z, hp - n, n);   // (1-z)*n + z*h
            }
        } else if (tid < 128) {
            // layer-0 combine for step i
            const int j  = tid - 64;
            const int xi = (i < TT) ? i : (TT - 1);
            float4 q0r = part4[j];       float4 q1r = part4[192 + j];
            float4 q0z = part4[j + 64];  float4 q1z = part4[192 + j + 64];
            float4 q0n = part4[j + 128]; float4 q1n = part4[192 + j + 128];
            float xv = x_lds[xi];
            float r = sigmoid_f(fmaf(xv, wih0_r, bih0_r) + q0r.x + q1r.x);
            float z = sigmoid_f(fmaf(xv, wih0_z, bih0_z) + q0z.x + q1z.x);
            float n = tanh_f(fmaf(r, q0n.x + q1n.x, fmaf(xv, wih0_n, bih0_n)));
            if (i < TT) {
                float hp = h0_lds[j];
                h0_lds[j] = fmaf(z, hp - n, n);
            }
        } else if (tid >= 448) {
            // head combine + reduce for y[i-2]
            const int j = tid - 448;
            float s = ph[j] + ph[64 + j] + bhead;
            float p = fmaxf(s, 0.f) * wh2_r;
            #pragma unroll
            for (int m = 1; m < 64; m <<= 1) p += __shfl_xor(p, m, 64);
            if (tid == 448 && i >= 2) out[(size_t)b * TT + (i - 2)] = p + bh2_s;
        }
        __syncthreads();
    }

    // final hidden states: hT[2,B,H]
    if (tid < HH) {
        out[YSZ +           b * HH + tid] = h0_lds[tid];
        out[YSZ + BB * HH + b * HH + tid] = h1_lds[tid];
    }
}

extern "C" void kernel_launch(void* const* d_in, const int* in_sizes, int n_in,
                              void* d_out, int out_size, void* d_ws, size_t ws_size,
                              hipStream_t stream) {
    const float* x     = (const float*)d_in[0];
    const float* h0in  = (const float*)d_in[1];
    const float* W_ih0 = (const float*)d_in[2];
    const float* W_hh0 = (const float*)d_in[3];
    const float* b_ih0 = (const float*)d_in[4];
    const float* b_hh0 = (const float*)d_in[5];
    const float* W_ih1 = (const float*)d_in[6];
    const float* W_hh1 = (const float*)d_in[7];
    const float* b_ih1 = (const float*)d_in[8];
    const float* b_hh1 = (const float*)d_in[9];
    const float* Wh1   = (const float*)d_in[10];
    const float* bh1   = (const float*)d_in[11];
    const float* Wh2   = (const float*)d_in[12];
    const float* bh2   = (const float*)d_in[13];
    float* out = (float*)d_out;

    gru_fused<<<dim3(BB), dim3(512), 0, stream>>>(
        x, h0in, W_ih0, W_hh0, b_ih0, b_hh0,
        W_ih1, W_hh1, b_ih1, b_hh1, Wh1, bh1, Wh2, bh2, out);
}